// Round 5
// baseline (218.701 us; speedup 1.0000x reference)
//
#include <hip/hip_runtime.h>
#include <math.h>

#define BATCH 512
#define DIM   1024
#define NCLUS 16384
#define TINV  20.0f   // 1/TEMP

typedef __attribute__((ext_vector_type(4))) float f32x4;
typedef __attribute__((ext_vector_type(8))) short bf16x8;

static __device__ __forceinline__ unsigned short f2bf(float f) {
  unsigned int u = __float_as_uint(f);
  u += 0x7FFFu + ((u >> 16) & 1u);   // round-to-nearest-even
  return (unsigned short)(u >> 16);
}

typedef const __attribute__((address_space(1))) unsigned int* gas1_t;
typedef __attribute__((address_space(3))) unsigned int* las3_t;
// async global->LDS, 16B per lane; LDS dest = wave-uniform base + lane*16
static __device__ __forceinline__ void gload16(const void* g, void* l) {
  __builtin_amdgcn_global_load_lds((gas1_t)g, (las3_t)l, 16, 0, 0);
}

// ---------------------------------------------------------------------------
// Kernel 1: row L2-normalize (both modalities), emit f32 + bf16 copies of x.
// Also zeroes the 2048-float accumulator region (rowsum + tgtlog).
// ---------------------------------------------------------------------------
__global__ void nrm_kernel(const float* __restrict__ in_rgb,
                           const float* __restrict__ in_ir,
                           float* __restrict__ xf,            // [2][512][1024]
                           unsigned short* __restrict__ xb,   // [2][512][1024]
                           float* __restrict__ accum) {       // 2048 floats
  int gid = blockIdx.x * blockDim.x + threadIdx.x;
  if (gid < 2048) accum[gid] = 0.0f;

  int row = blockIdx.x;
  int mod = row >> 9;
  int r   = row & 511;
  const float* in = (mod ? in_ir : in_rgb) + (size_t)r * DIM;
  float* xo          = xf + ((size_t)mod * BATCH + r) * DIM;
  unsigned short* xbo = xb + ((size_t)mod * BATCH + r) * DIM;

  int t = threadIdx.x;
  float4 v = ((const float4*)in)[t];
  float ss = v.x*v.x + v.y*v.y + v.z*v.z + v.w*v.w;
#pragma unroll
  for (int m = 1; m < 64; m <<= 1) ss += __shfl_xor(ss, m, 64);
  __shared__ float red[4];
  if ((t & 63) == 0) red[t >> 6] = ss;
  __syncthreads();
  float inv = 1.0f / fmaxf(sqrtf(red[0] + red[1] + red[2] + red[3]), 1e-12f);
  float4 o = make_float4(v.x * inv, v.y * inv, v.z * inv, v.w * inv);
  ((float4*)xo)[t] = o;
  ushort4 ob = make_ushort4(f2bf(o.x), f2bf(o.y), f2bf(o.z), f2bf(o.w));
  ((ushort4*)xbo)[t] = ob;
}

// ---------------------------------------------------------------------------
// Kernel 2: bank copy to d_out (f32 exact) + fused bf16 conversion of F.
// out is only 8B-aligned (d_out+2 floats) -> float2 stores there.
// ---------------------------------------------------------------------------
__global__ void cvtcopy_kernel(const float* __restrict__ f_rgb,
                               const float* __restrict__ f_ir,
                               float* __restrict__ out,           // out + 2
                               unsigned short* __restrict__ fb,   // [2][16384][1024] bf16
                               int precvt) {
  const size_t n4 = (size_t)NCLUS * DIM / 4;   // float4 per bank
  size_t stride = (size_t)gridDim.x * blockDim.x;
  for (size_t i = (size_t)blockIdx.x * blockDim.x + threadIdx.x; i < 2 * n4; i += stride) {
    const float4 v = (i < n4) ? ((const float4*)f_rgb)[i] : ((const float4*)f_ir)[i - n4];
    float2* o2 = (float2*)(out + 4 * i);
    o2[0] = make_float2(v.x, v.y);
    o2[1] = make_float2(v.z, v.w);
    if (precvt)
      ((ushort4*)fb)[i] = make_ushort4(f2bf(v.x), f2bf(v.y), f2bf(v.z), f2bf(v.w));
  }
}

// ---------------------------------------------------------------------------
// Kernel 3: bf16 MFMA GEMM with 3-deep pipeline + COUNTED vmcnt (T4).
// Tile 128x128, BK=32, 4 waves (2x2) each 64x64.
// Per thread each STAGE issues 4 global_load_lds; at each barrier we wait
// vmcnt(4): tile t+1's loads retired, tile t+2's stay in flight ACROSS the
// barrier (never drain to 0 in the main loop — AITER/HK pattern).
// grid: (128 nt, 8 = mod*4+bt); linear dispatch idx % 8 == nt % 8 -> all
// blocks sharing an F panel land on one XCD (L2 reuse).
// ---------------------------------------------------------------------------
#define BM 128
#define BN 128
#define BK 32
#define NT_STEPS (DIM / BK)   // 32

template<int PRECVT>
__global__ void gemm_lse_kernel(const unsigned short* __restrict__ xb,
                                const unsigned short* __restrict__ fb,
                                const float* __restrict__ f_rgb,
                                const float* __restrict__ f_ir,
                                const int* __restrict__ t_rgb,
                                const int* __restrict__ t_ir,
                                float* __restrict__ rowsum,   // [2][512]
                                float* __restrict__ tgtlog) { // [2][512]
  const int nt  = blockIdx.x;        // 0..127
  const int bt  = blockIdx.y & 3;    // batch tile
  const int mod = blockIdx.y >> 2;   // modality

  const unsigned short* X  = xb + ((size_t)mod * BATCH + bt * BM) * DIM;
  const unsigned short* Bb = fb + ((size_t)mod * NCLUS + nt * BN) * DIM;
  const float* Ff = (mod ? f_ir : f_rgb) + (size_t)nt * BN * DIM;
  const int*   tg = mod ? t_ir : t_rgb;
  float* rs = rowsum + mod * BATCH;
  float* tl = tgtlog + mod * BATCH;

  __shared__ __align__(16) unsigned short As[3][BM * BK];
  __shared__ __align__(16) unsigned short Bs[3][BN * BK];

  const int tid  = threadIdx.x;
  const int wid  = tid >> 6;
  const int lane = tid & 63;
  const int wr = wid >> 1, wc = wid & 1;
  const int l15 = lane & 15, lhi = lane >> 4;

  f32x4 acc[4][4];
#pragma unroll
  for (int m = 0; m < 4; ++m)
#pragma unroll
    for (int n = 0; n < 4; ++n) acc[m][n] = (f32x4){0.f, 0.f, 0.f, 0.f};

  auto STAGE = [&](int buf, int kk) {   // 4 VMEM ops per thread (PRECVT=1)
#pragma unroll
    for (int i = 0; i < 2; ++i) {
      int q = i * 256 + tid;           // 0..511, chunk q -> LDS byte q*16
      gload16(X + (size_t)(q >> 2) * DIM + kk + (q & 3) * 8,
              &As[buf][(size_t)(i * 256 + wid * 64) * 8]);
      if (PRECVT)
        gload16(Bb + (size_t)(q >> 2) * DIM + kk + (q & 3) * 8,
                &Bs[buf][(size_t)(i * 256 + wid * 64) * 8]);
    }
    if (!PRECVT) {
#pragma unroll
      for (int i = 0; i < 4; ++i) {
        int id = i * 256 + tid;        // 0..1023
        int row = id >> 3, c4 = (id & 7) << 2;
        float4 v = *(const float4*)(Ff + (size_t)row * DIM + kk + c4);
        *(ushort4*)(&Bs[buf][row * BK + c4]) =
            make_ushort4(f2bf(v.x), f2bf(v.y), f2bf(v.z), f2bf(v.w));
      }
    }
  };

  auto COMPUTE = [&](int buf) {
    bf16x8 a[4], b[4];
#pragma unroll
    for (int m = 0; m < 4; ++m)
      a[m] = *(const bf16x8*)(&As[buf][(wr * 64 + m * 16 + l15) * BK + lhi * 8]);
#pragma unroll
    for (int n = 0; n < 4; ++n)
      b[n] = *(const bf16x8*)(&Bs[buf][(wc * 64 + n * 16 + l15) * BK + lhi * 8]);
#pragma unroll
    for (int m = 0; m < 4; ++m)
#pragma unroll
      for (int n = 0; n < 4; ++n)
        acc[m][n] = __builtin_amdgcn_mfma_f32_16x16x32_bf16(a[m], b[n], acc[m][n], 0, 0, 0);
  };

  if (PRECVT) {
    // prologue: tiles 0 and 1 in flight; wait only tile 0 (vmcnt(4))
    STAGE(0, 0);
    STAGE(1, BK);
    asm volatile("s_waitcnt vmcnt(4)" ::: "memory");
    __builtin_amdgcn_s_barrier();
    for (int t = 0; t < NT_STEPS; ++t) {
      if (t + 2 < NT_STEPS) STAGE((t + 2) % 3, (t + 2) * BK);
      COMPUTE(t % 3);
      if (t < NT_STEPS - 1) {
        // all my ds_reads retired before next iter's DMA may hit this buffer
        asm volatile("s_waitcnt lgkmcnt(0)" ::: "memory");
        if (t < NT_STEPS - 2)
          asm volatile("s_waitcnt vmcnt(4)" ::: "memory");  // tile t+1 landed
        else
          asm volatile("s_waitcnt vmcnt(0)" ::: "memory");  // tail drain
        __builtin_amdgcn_s_barrier();
      }
    }
  } else {
    // fallback: 2-buffer __syncthreads pipeline (reg-staged B with cvt)
    STAGE(0, 0);
    __syncthreads();
    int cur = 0;
    for (int s = 1; s < NT_STEPS; ++s) {
      STAGE(cur ^ 1, s * BK);
      COMPUTE(cur);
      __syncthreads();
      cur ^= 1;
    }
    COMPUTE(cur);
  }

  // epilogue: exp-sum reduce over this tile's 128 columns + target capture
#pragma unroll
  for (int m = 0; m < 4; ++m) {
    const int browbase = bt * BM + wr * 64 + m * 16 + lhi * 4;
    float esum[4];
#pragma unroll
    for (int j = 0; j < 4; ++j) {
      const int brow = browbase + j;
      const int t = tg[brow];
      float e = 0.f;
#pragma unroll
      for (int n = 0; n < 4; ++n) {
        float logit = acc[m][n][j] * TINV;
        e += __expf(logit);
        int col = nt * BN + wc * 64 + n * 16 + l15;
        if (col == t) tl[brow] = logit;
      }
      esum[j] = e;
    }
#pragma unroll
    for (int j = 0; j < 4; ++j) {
      float e = esum[j];
      e += __shfl_xor(e, 1, 64);
      e += __shfl_xor(e, 2, 64);
      e += __shfl_xor(e, 4, 64);
      e += __shfl_xor(e, 8, 64);
      if (l15 == 0) atomicAdd(rs + browbase + j, e);
    }
  }
}

// ---------------------------------------------------------------------------
// Kernel 4: loss = mean(log(rowsum) - tgtlog) per modality
// ---------------------------------------------------------------------------
__global__ void loss_kernel(const float* __restrict__ rowsum,
                            const float* __restrict__ tgtlog,
                            float* __restrict__ out) {
  int t = threadIdx.x;  // 512
  float lr = logf(rowsum[t]) - tgtlog[t];
  float li = logf(rowsum[BATCH + t]) - tgtlog[BATCH + t];
#pragma unroll
  for (int m = 1; m < 64; m <<= 1) { lr += __shfl_xor(lr, m, 64); li += __shfl_xor(li, m, 64); }
  __shared__ float sr[8], si[8];
  if ((t & 63) == 0) { sr[t >> 6] = lr; si[t >> 6] = li; }
  __syncthreads();
  if (t == 0) {
    float a = 0.f, b = 0.f;
#pragma unroll
    for (int i = 0; i < 8; ++i) { a += sr[i]; b += si[i]; }
    out[0] = a * (1.0f / BATCH);
    out[1] = b * (1.0f / BATCH);
  }
}

// ---------------------------------------------------------------------------
// Kernel 5: sequential momentum update chains on the copied banks.
// ---------------------------------------------------------------------------
__global__ void mom_kernel(const int* __restrict__ t_rgb,
                           const int* __restrict__ t_ir,
                           const float* __restrict__ xf,   // [2][512][1024]
                           float* __restrict__ out) {      // out + 2 base
  const int i   = blockIdx.x;
  const int mod = blockIdx.y;
  const int* tg = mod ? t_ir : t_rgb;
  const int y = tg[i];
  for (int j = 0; j < i; ++j)
    if (tg[j] == y) return;          // uniform: another block owns this chain

  const float* x = xf + (size_t)mod * BATCH * DIM;
  float* rowp = out + (size_t)mod * NCLUS * DIM + (size_t)y * DIM;

  const int t = threadIdx.x;  // 256
  float2 r0 = ((const float2*)rowp)[t];
  float2 r1 = ((const float2*)rowp)[t + 256];
  __shared__ float red[4];

  for (int j = i; j < BATCH; ++j) {
    if (tg[j] != y) continue;        // uniform
    const float2* xr = (const float2*)(x + (size_t)j * DIM);
    float2 x0 = xr[t], x1 = xr[t + 256];
    r0.x = 0.9f * r0.x + 0.1f * x0.x;
    r0.y = 0.9f * r0.y + 0.1f * x0.y;
    r1.x = 0.9f * r1.x + 0.1f * x1.x;
    r1.y = 0.9f * r1.y + 0.1f * x1.y;
    float ss = r0.x*r0.x + r0.y*r0.y + r1.x*r1.x + r1.y*r1.y;
#pragma unroll
    for (int m = 1; m < 64; m <<= 1) ss += __shfl_xor(ss, m, 64);
    if ((t & 63) == 0) red[t >> 6] = ss;
    __syncthreads();
    float tot = red[0] + red[1] + red[2] + red[3];
    __syncthreads();
    float inv = 1.0f / sqrtf(tot);
    r0.x *= inv; r0.y *= inv; r1.x *= inv; r1.y *= inv;
  }
  ((float2*)rowp)[t] = r0;
  ((float2*)rowp)[t + 256] = r1;
}

// ---------------------------------------------------------------------------
extern "C" void kernel_launch(void* const* d_in, const int* in_sizes, int n_in,
                              void* d_out, int out_size, void* d_ws, size_t ws_size,
                              hipStream_t stream) {
  (void)in_sizes; (void)n_in; (void)out_size;
  const float* in_rgb = (const float*)d_in[0];
  const float* in_ir  = (const float*)d_in[1];
  const int*   t_rgb  = (const int*)d_in[2];
  const int*   t_ir   = (const int*)d_in[3];
  const float* f_rgb  = (const float*)d_in[4];
  const float* f_ir   = (const float*)d_in[5];
  float* out = (float*)d_out;

  char* ws = (char*)d_ws;
  float*          xf     = (float*)ws;                       // 4 MB  [2][512][1024] f32
  unsigned short* xb     = (unsigned short*)(ws + (4u<<20)); // 2 MB  [2][512][1024] bf16
  float*          rowsum = (float*)(ws + (6u<<20));          // 2048 f32 (rowsum+tgtlog)
  float*          tgtlog = rowsum + 1024;
  unsigned short* fb     = (unsigned short*)(ws + (8u<<20)); // 64 MB [2][16384][1024] bf16
  const int precvt = (ws_size >= ((size_t)72 << 20)) ? 1 : 0;

  nrm_kernel<<<1024, 256, 0, stream>>>(in_rgb, in_ir, xf, xb, rowsum);
  cvtcopy_kernel<<<2048, 256, 0, stream>>>(f_rgb, f_ir, out + 2, fb, precvt);
  if (precvt)
    gemm_lse_kernel<1><<<dim3(128, 8), 256, 0, stream>>>(xb, fb, f_rgb, f_ir,
                                                         t_rgb, t_ir, rowsum, tgtlog);
  else
    gemm_lse_kernel<0><<<dim3(128, 8), 256, 0, stream>>>(xb, fb, f_rgb, f_ir,
                                                         t_rgb, t_ir, rowsum, tgtlog);
  mom_kernel<<<dim3(512, 2), 256, 0, stream>>>(t_rgb, t_ir, xf, out + 2);
  loss_kernel<<<1, 512, 0, stream>>>(rowsum, tgtlog, out);
}

// Round 6
// 195.535 us; speedup vs baseline: 1.1185x; 1.1185x over previous
//
#include <hip/hip_runtime.h>
#include <math.h>

#define BATCH 512
#define DIM   1024
#define NCLUS 16384
#define TINV  20.0f   // 1/TEMP

typedef __attribute__((ext_vector_type(4))) float f32x4;
typedef __attribute__((ext_vector_type(8))) short bf16x8;

static __device__ __forceinline__ unsigned short f2bf(float f) {
  unsigned int u = __float_as_uint(f);
  u += 0x7FFFu + ((u >> 16) & 1u);   // round-to-nearest-even
  return (unsigned short)(u >> 16);
}

typedef const __attribute__((address_space(1))) unsigned int* gas1_t;
typedef __attribute__((address_space(3))) unsigned int* las3_t;
// async global->LDS, 16B per lane; LDS dest = wave-uniform base + lane*16
static __device__ __forceinline__ void gload16(const void* g, void* l) {
  __builtin_amdgcn_global_load_lds((gas1_t)g, (las3_t)l, 16, 0, 0);
}

// ---------------------------------------------------------------------------
// Kernel 1: row L2-normalize (both modalities), emit f32 + bf16 copies of x.
// Also zeroes the 2048-float accumulator region (rowsum + tgtlog).
// ---------------------------------------------------------------------------
__global__ void nrm_kernel(const float* __restrict__ in_rgb,
                           const float* __restrict__ in_ir,
                           float* __restrict__ xf,            // [2][512][1024]
                           unsigned short* __restrict__ xb,   // [2][512][1024]
                           float* __restrict__ accum) {       // 2048 floats
  int gid = blockIdx.x * blockDim.x + threadIdx.x;
  if (gid < 2048) accum[gid] = 0.0f;

  int row = blockIdx.x;
  int mod = row >> 9;
  int r   = row & 511;
  const float* in = (mod ? in_ir : in_rgb) + (size_t)r * DIM;
  float* xo          = xf + ((size_t)mod * BATCH + r) * DIM;
  unsigned short* xbo = xb + ((size_t)mod * BATCH + r) * DIM;

  int t = threadIdx.x;
  float4 v = ((const float4*)in)[t];
  float ss = v.x*v.x + v.y*v.y + v.z*v.z + v.w*v.w;
#pragma unroll
  for (int m = 1; m < 64; m <<= 1) ss += __shfl_xor(ss, m, 64);
  __shared__ float red[4];
  if ((t & 63) == 0) red[t >> 6] = ss;
  __syncthreads();
  float inv = 1.0f / fmaxf(sqrtf(red[0] + red[1] + red[2] + red[3]), 1e-12f);
  float4 o = make_float4(v.x * inv, v.y * inv, v.z * inv, v.w * inv);
  ((float4*)xo)[t] = o;
  ushort4 ob = make_ushort4(f2bf(o.x), f2bf(o.y), f2bf(o.z), f2bf(o.w));
  ((ushort4*)xbo)[t] = ob;
}

// ---------------------------------------------------------------------------
// Kernel 2: FUSED bf16 MFMA GEMM + bank copy + exp-sum/target capture.
// B-side reads f32 F directly (reg-staged, in-register cvt, ds_write);
// bt==0 blocks also stream the loaded f32 panel to d_out (the copy rides
// the GEMM's idle memory pipe). A-side via global_load_lds. 2-buf LDS,
// issue-early loads / write-late LDS (T14).
// Tile 128x128, BK=32, 4 waves (2x2) each 64x64.
// grid: (128 nt, 8 = mod*4+bt); linear dispatch idx % 8 == nt % 8 -> all
// blocks sharing an F panel land on one XCD (L2 serves 3 of 4 panel reads).
// ---------------------------------------------------------------------------
#define BM 128
#define BN 128
#define BK 32
#define NSTEP (DIM / BK)   // 32

__global__ void gemm_lse_kernel(const unsigned short* __restrict__ xb,
                                const float* __restrict__ f_rgb,
                                const float* __restrict__ f_ir,
                                const int* __restrict__ t_rgb,
                                const int* __restrict__ t_ir,
                                float* __restrict__ outc,     // d_out + 2
                                float* __restrict__ rowsum,   // [2][512]
                                float* __restrict__ tgtlog) { // [2][512]
  const int nt  = blockIdx.x;        // 0..127
  const int bt  = blockIdx.y & 3;    // batch tile
  const int mod = blockIdx.y >> 2;   // modality

  const unsigned short* X = xb + ((size_t)mod * BATCH + bt * BM) * DIM;
  const float* Ff = (mod ? f_ir : f_rgb) + (size_t)nt * BN * DIM;
  float* Oc = outc + ((size_t)mod * NCLUS + (size_t)nt * BN) * DIM;
  const int*   tg = mod ? t_ir : t_rgb;
  float* rs = rowsum + mod * BATCH;
  float* tl = tgtlog + mod * BATCH;

  __shared__ __align__(16) unsigned short As[2][BM * BK];
  __shared__ __align__(16) unsigned short Bs[2][BN * BK];

  const int tid  = threadIdx.x;
  const int wid  = tid >> 6;
  const int lane = tid & 63;
  const int wr = wid >> 1, wc = wid & 1;
  const int l15 = lane & 15, lhi = lane >> 4;

  f32x4 acc[4][4];
#pragma unroll
  for (int m = 0; m < 4; ++m)
#pragma unroll
    for (int n = 0; n < 4; ++n) acc[m][n] = (f32x4){0.f, 0.f, 0.f, 0.f};

  // B: 128 rows x 32 f32 cols; 4 float4 per thread. row=id>>3, c4=(id&7)*4
  auto B_LOAD = [&](float4* br, int kk) {
#pragma unroll
    for (int i = 0; i < 4; ++i) {
      int id = i * 256 + tid;
      br[i] = *(const float4*)(Ff + (size_t)(id >> 3) * DIM + kk + ((id & 7) << 2));
    }
  };
  auto B_WRITE = [&](int buf, const float4* br, int kk) {
#pragma unroll
    for (int i = 0; i < 4; ++i) {
      int id = i * 256 + tid;
      int row = id >> 3, c4 = (id & 7) << 2;
      float4 v = br[i];
      *(ushort4*)(&Bs[buf][row * BK + c4]) =
          make_ushort4(f2bf(v.x), f2bf(v.y), f2bf(v.z), f2bf(v.w));
      if (bt == 0) {  // fused bank copy (uniform branch); dest 8B-aligned
        float2* o2 = (float2*)(Oc + (size_t)row * DIM + kk + c4);
        o2[0] = make_float2(v.x, v.y);
        o2[1] = make_float2(v.z, v.w);
      }
    }
  };
  // A: 128 rows x 32 bf16 cols via global_load_lds; chunk q -> LDS byte q*16
  auto A_STAGE = [&](int buf, int kk) {
#pragma unroll
    for (int i = 0; i < 2; ++i) {
      int q = i * 256 + tid;           // 0..511
      gload16(X + (size_t)(q >> 2) * DIM + kk + (q & 3) * 8,
              &As[buf][(size_t)(i * 256 + wid * 64) * 8]);
    }
  };

  auto COMPUTE = [&](int buf) {
    bf16x8 a[4], b[4];
#pragma unroll
    for (int m = 0; m < 4; ++m)
      a[m] = *(const bf16x8*)(&As[buf][(wr * 64 + m * 16 + l15) * BK + lhi * 8]);
#pragma unroll
    for (int n = 0; n < 4; ++n)
      b[n] = *(const bf16x8*)(&Bs[buf][(wc * 64 + n * 16 + l15) * BK + lhi * 8]);
#pragma unroll
    for (int m = 0; m < 4; ++m)
#pragma unroll
      for (int n = 0; n < 4; ++n)
        acc[m][n] = __builtin_amdgcn_mfma_f32_16x16x32_bf16(a[m], b[n], acc[m][n], 0, 0, 0);
  };

  // prologue: tile 0
  {
    float4 br[4];
    B_LOAD(br, 0);
    A_STAGE(0, 0);
    B_WRITE(0, br, 0);
  }
  __syncthreads();
  int cur = 0;
  for (int s = 1; s < NSTEP; ++s) {
    float4 brn[4];
    B_LOAD(brn, s * BK);       // issue next tile's B loads early
    COMPUTE(cur);              // latency hides under MFMA phase
    A_STAGE(cur ^ 1, s * BK);
    B_WRITE(cur ^ 1, brn, s * BK);
    __syncthreads();
    cur ^= 1;
  }
  COMPUTE(cur);                // last tile

  // epilogue: exp-sum reduce over this tile's 128 columns + target capture
#pragma unroll
  for (int m = 0; m < 4; ++m) {
    const int browbase = bt * BM + wr * 64 + m * 16 + lhi * 4;
    float esum[4];
#pragma unroll
    for (int j = 0; j < 4; ++j) {
      const int brow = browbase + j;
      const int t = tg[brow];
      float e = 0.f;
#pragma unroll
      for (int n = 0; n < 4; ++n) {
        float logit = acc[m][n][j] * TINV;
        e += __expf(logit);
        int col = nt * BN + wc * 64 + n * 16 + l15;
        if (col == t) tl[brow] = logit;
      }
      esum[j] = e;
    }
#pragma unroll
    for (int j = 0; j < 4; ++j) {
      float e = esum[j];
      e += __shfl_xor(e, 1, 64);
      e += __shfl_xor(e, 2, 64);
      e += __shfl_xor(e, 4, 64);
      e += __shfl_xor(e, 8, 64);
      if (l15 == 0) atomicAdd(rs + browbase + j, e);
    }
  }
}

// ---------------------------------------------------------------------------
// Kernel 3: loss = mean(log(rowsum) - tgtlog) per modality
// ---------------------------------------------------------------------------
__global__ void loss_kernel(const float* __restrict__ rowsum,
                            const float* __restrict__ tgtlog,
                            float* __restrict__ out) {
  int t = threadIdx.x;  // 512
  float lr = logf(rowsum[t]) - tgtlog[t];
  float li = logf(rowsum[BATCH + t]) - tgtlog[BATCH + t];
#pragma unroll
  for (int m = 1; m < 64; m <<= 1) { lr += __shfl_xor(lr, m, 64); li += __shfl_xor(li, m, 64); }
  __shared__ float sr[8], si[8];
  if ((t & 63) == 0) { sr[t >> 6] = lr; si[t >> 6] = li; }
  __syncthreads();
  if (t == 0) {
    float a = 0.f, b = 0.f;
#pragma unroll
    for (int i = 0; i < 8; ++i) { a += sr[i]; b += si[i]; }
    out[0] = a * (1.0f / BATCH);
    out[1] = b * (1.0f / BATCH);
  }
}

// ---------------------------------------------------------------------------
// Kernel 4: sequential momentum update chains on the copied banks.
// ---------------------------------------------------------------------------
__global__ void mom_kernel(const int* __restrict__ t_rgb,
                           const int* __restrict__ t_ir,
                           const float* __restrict__ xf,   // [2][512][1024]
                           float* __restrict__ out) {      // out + 2 base
  const int i   = blockIdx.x;
  const int mod = blockIdx.y;
  const int* tg = mod ? t_ir : t_rgb;
  const int y = tg[i];
  for (int j = 0; j < i; ++j)
    if (tg[j] == y) return;          // uniform: another block owns this chain

  const float* x = xf + (size_t)mod * BATCH * DIM;
  float* rowp = out + (size_t)mod * NCLUS * DIM + (size_t)y * DIM;

  const int t = threadIdx.x;  // 256
  float2 r0 = ((const float2*)rowp)[t];
  float2 r1 = ((const float2*)rowp)[t + 256];
  __shared__ float red[4];

  for (int j = i; j < BATCH; ++j) {
    if (tg[j] != y) continue;        // uniform
    const float2* xr = (const float2*)(x + (size_t)j * DIM);
    float2 x0 = xr[t], x1 = xr[t + 256];
    r0.x = 0.9f * r0.x + 0.1f * x0.x;
    r0.y = 0.9f * r0.y + 0.1f * x0.y;
    r1.x = 0.9f * r1.x + 0.1f * x1.x;
    r1.y = 0.9f * r1.y + 0.1f * x1.y;
    float ss = r0.x*r0.x + r0.y*r0.y + r1.x*r1.x + r1.y*r1.y;
#pragma unroll
    for (int m = 1; m < 64; m <<= 1) ss += __shfl_xor(ss, m, 64);
    if ((t & 63) == 0) red[t >> 6] = ss;
    __syncthreads();
    float tot = red[0] + red[1] + red[2] + red[3];
    __syncthreads();
    float inv = 1.0f / sqrtf(tot);
    r0.x *= inv; r0.y *= inv; r1.x *= inv; r1.y *= inv;
  }
  ((float2*)rowp)[t] = r0;
  ((float2*)rowp)[t + 256] = r1;
}

// ---------------------------------------------------------------------------
extern "C" void kernel_launch(void* const* d_in, const int* in_sizes, int n_in,
                              void* d_out, int out_size, void* d_ws, size_t ws_size,
                              hipStream_t stream) {
  (void)in_sizes; (void)n_in; (void)out_size; (void)ws_size;
  const float* in_rgb = (const float*)d_in[0];
  const float* in_ir  = (const float*)d_in[1];
  const int*   t_rgb  = (const int*)d_in[2];
  const int*   t_ir   = (const int*)d_in[3];
  const float* f_rgb  = (const float*)d_in[4];
  const float* f_ir   = (const float*)d_in[5];
  float* out = (float*)d_out;

  char* ws = (char*)d_ws;
  float*          xf     = (float*)ws;                       // 4 MB  [2][512][1024] f32
  unsigned short* xb     = (unsigned short*)(ws + (4u<<20)); // 2 MB  [2][512][1024] bf16
  float*          rowsum = (float*)(ws + (6u<<20));          // 2048 f32 (rowsum+tgtlog)
  float*          tgtlog = rowsum + 1024;

  nrm_kernel<<<1024, 256, 0, stream>>>(in_rgb, in_ir, xf, xb, rowsum);
  gemm_lse_kernel<<<dim3(128, 8), 256, 0, stream>>>(xb, f_rgb, f_ir, t_rgb, t_ir,
                                                    out + 2, rowsum, tgtlog);
  mom_kernel<<<dim3(512, 2), 256, 0, stream>>>(t_rgb, t_ir, xf, out + 2);
  loss_kernel<<<1, 512, 0, stream>>>(rowsum, tgtlog, out);
}

// Round 8
// 193.925 us; speedup vs baseline: 1.1278x; 1.0083x over previous
//
#include <hip/hip_runtime.h>
#include <math.h>

#define BATCH 512
#define DIM   1024
#define NCLUS 16384
#define TINV  20.0f   // 1/TEMP

typedef __attribute__((ext_vector_type(4))) float f32x4;
typedef __attribute__((ext_vector_type(2))) float f32x2;
typedef __attribute__((ext_vector_type(8))) short bf16x8;

static __device__ __forceinline__ unsigned short f2bf(float f) {
  unsigned int u = __float_as_uint(f);
  u += 0x7FFFu + ((u >> 16) & 1u);   // round-to-nearest-even
  return (unsigned short)(u >> 16);
}

typedef const __attribute__((address_space(1))) unsigned int* gas1_t;
typedef __attribute__((address_space(3))) unsigned int* las3_t;
// async global->LDS, 16B per lane; LDS dest = wave-uniform base + lane*16
static __device__ __forceinline__ void gload16(const void* g, void* l) {
  __builtin_amdgcn_global_load_lds((gas1_t)g, (las3_t)l, 16, 0, 0);
}

// ---------------------------------------------------------------------------
// Kernel 1: row L2-normalize (both modalities), emit f32 + bf16 copies of x.
// Also zeroes the 2048-float accumulator region (rowsum + tgtlog).
// ---------------------------------------------------------------------------
__global__ void nrm_kernel(const float* __restrict__ in_rgb,
                           const float* __restrict__ in_ir,
                           float* __restrict__ xf,            // [2][512][1024]
                           unsigned short* __restrict__ xb,   // [2][512][1024]
                           float* __restrict__ accum) {       // 2048 floats
  int gid = blockIdx.x * blockDim.x + threadIdx.x;
  if (gid < 2048) accum[gid] = 0.0f;

  int row = blockIdx.x;
  int mod = row >> 9;
  int r   = row & 511;
  const float* in = (mod ? in_ir : in_rgb) + (size_t)r * DIM;
  float* xo          = xf + ((size_t)mod * BATCH + r) * DIM;
  unsigned short* xbo = xb + ((size_t)mod * BATCH + r) * DIM;

  int t = threadIdx.x;
  float4 v = ((const float4*)in)[t];
  float ss = v.x*v.x + v.y*v.y + v.z*v.z + v.w*v.w;
#pragma unroll
  for (int m = 1; m < 64; m <<= 1) ss += __shfl_xor(ss, m, 64);
  __shared__ float red[4];
  if ((t & 63) == 0) red[t >> 6] = ss;
  __syncthreads();
  float inv = 1.0f / fmaxf(sqrtf(red[0] + red[1] + red[2] + red[3]), 1e-12f);
  float4 o = make_float4(v.x * inv, v.y * inv, v.z * inv, v.w * inv);
  ((float4*)xo)[t] = o;
  ushort4 ob = make_ushort4(f2bf(o.x), f2bf(o.y), f2bf(o.z), f2bf(o.w));
  ((ushort4*)xbo)[t] = ob;
}

// ---------------------------------------------------------------------------
// Kernel 2: bank copy to d_out (f32 exact, nontemporal) + bf16 convert of F.
// out is only 8B-aligned (d_out+2 floats) -> f32x2 stores there.
// ---------------------------------------------------------------------------
__global__ void cvtcopy_kernel(const float* __restrict__ f_rgb,
                               const float* __restrict__ f_ir,
                               float* __restrict__ out,           // out + 2
                               unsigned short* __restrict__ fb) { // [2][16384][1024] bf16
  const size_t n4 = (size_t)NCLUS * DIM / 4;   // f32x4 per bank
  size_t stride = (size_t)gridDim.x * blockDim.x;
  for (size_t i = (size_t)blockIdx.x * blockDim.x + threadIdx.x; i < 2 * n4; i += stride) {
    const f32x4* src = (i < n4) ? ((const f32x4*)f_rgb) + i
                                : ((const f32x4*)f_ir) + (i - n4);
    const f32x4 v = __builtin_nontemporal_load(src);
    f32x2* o2 = (f32x2*)(out + 4 * i);
    __builtin_nontemporal_store((f32x2){v.x, v.y}, o2);
    __builtin_nontemporal_store((f32x2){v.z, v.w}, o2 + 1);
    ((ushort4*)fb)[i] = make_ushort4(f2bf(v.x), f2bf(v.y), f2bf(v.z), f2bf(v.w));
  }
}

// ---------------------------------------------------------------------------
// Kernel 3: 256x256 bf16 MFMA GEMM + fused exp-sum / target capture.
// 512 threads = 8 waves (2 M x 4 N), per-wave output 128x64, acc[8][4].
// K-tile BK=32, 4-slot LDS ring (128 KB), stage KT i+2 at iter i,
// counted s_waitcnt vmcnt(4) once per iteration (T4), 2 phases/iter with
// setprio MFMA clusters (T3/T5). Conflict-free LDS reads via read-side XOR
// byte ^= (row&6)<<3 + inverse-swizzled global source chunks (T2, rule #21:
// linear gload_lds dest, pre-swizzled per-lane SOURCE, swizzled READ).
// grid (64 nt, 4 = mod*2+bt): linear idx % 8 groups panel-sharing blocks
// (same nt, bt=0/1) on one XCD.
// ---------------------------------------------------------------------------
#define BM 256
#define BN 256
#define BK 32
#define KT_N (DIM / BK)   // 32 K-tiles

__launch_bounds__(512, 2)
__global__ void gemm_lse_kernel(const unsigned short* __restrict__ xb,
                                const unsigned short* __restrict__ fb,
                                const int* __restrict__ t_rgb,
                                const int* __restrict__ t_ir,
                                float* __restrict__ rowsum,   // [2][512]
                                float* __restrict__ tgtlog) { // [2][512]
  const int nt  = blockIdx.x;        // 0..63
  const int bt  = blockIdx.y & 1;    // batch tile
  const int mod = blockIdx.y >> 1;   // modality

  const unsigned short* X = xb + ((size_t)mod * BATCH + bt * BM) * DIM;
  const unsigned short* F = fb + ((size_t)mod * NCLUS + (size_t)nt * BN) * DIM;
  const int* tg = mod ? t_ir : t_rgb;
  float* rs = rowsum + mod * BATCH;
  float* tl = tgtlog + mod * BATCH;

  __shared__ __align__(16) unsigned short Ab[4][BM * BK];  // 64 KB
  __shared__ __align__(16) unsigned short Bb[4][BN * BK];  // 64 KB

  const int tid  = threadIdx.x;        // 0..511
  const int wid  = tid >> 6;           // 0..7
  const int lane = tid & 63;
  const int wr = wid >> 2, wc = wid & 3;
  const int l15 = lane & 15, lhi = lane >> 4;
  const int sw = (l15 & 6) << 3;       // read-side bank-spread XOR (bytes)

  f32x4 acc[8][4];
#pragma unroll
  for (int m = 0; m < 8; ++m)
#pragma unroll
    for (int n = 0; n < 4; ++n) acc[m][n] = (f32x4){0.f, 0.f, 0.f, 0.f};

  // stage one 16 KB tile (A or B) of K-tile kt into slot sl: 2 gload16/thread.
  // source chunk is inverse-swizzled: cs = (q&3) ^ ((q>>3)&3)  (involution,
  // row q>>2 unchanged) so the XOR'd read below retrieves the right bytes.
  auto STAGE_A = [&](int sl, int kt) {
#pragma unroll
    for (int c = 0; c < 2; ++c) {
      int q = c * 512 + tid;                       // chunk 0..1023
      int cs = (q & 3) ^ ((q >> 3) & 3);
      gload16(X + (size_t)(q >> 2) * DIM + kt * BK + cs * 8,
              &Ab[sl][(c * 512 + wid * 64) * 8]);
    }
  };
  auto STAGE_B = [&](int sl, int kt) {
#pragma unroll
    for (int c = 0; c < 2; ++c) {
      int q = c * 512 + tid;
      int cs = (q & 3) ^ ((q >> 3) & 3);
      gload16(F + (size_t)(q >> 2) * DIM + kt * BK + cs * 8,
              &Bb[sl][(c * 512 + wid * 64) * 8]);
    }
  };
  auto LDA = [&](int sl, int row) {
    return *(const bf16x8*)((const char*)Ab[sl] + ((row * (BK * 2) + lhi * 16) ^ sw));
  };
  auto LDB = [&](int sl, int row) {
    return *(const bf16x8*)((const char*)Bb[sl] + ((row * (BK * 2) + lhi * 16) ^ sw));
  };

  auto ITERATION = [&](int i, bool doStage, bool vm4) {
    const int sl = i & 3, sp = (i + 2) & 3;
    bf16x8 a[4], b[4];
    // ---- phase 0: rows wr*128 + [0,64) ; all 4 n ----
#pragma unroll
    for (int n = 0; n < 4; ++n) b[n] = LDB(sl, wc * 64 + n * 16 + l15);
#pragma unroll
    for (int m = 0; m < 4; ++m) a[m] = LDA(sl, wr * 128 + m * 16 + l15);
    if (doStage) STAGE_A(sp, i + 2);
    __builtin_amdgcn_s_barrier();
    __builtin_amdgcn_s_setprio(1);
#pragma unroll
    for (int m = 0; m < 4; ++m)
#pragma unroll
      for (int n = 0; n < 4; ++n)
        acc[m][n] = __builtin_amdgcn_mfma_f32_16x16x32_bf16(a[m], b[n], acc[m][n], 0, 0, 0);
    __builtin_amdgcn_s_setprio(0);
    __builtin_amdgcn_s_barrier();
    // ---- phase 1: rows wr*128 + [64,128) ; b[] still live ----
#pragma unroll
    for (int m = 0; m < 4; ++m) a[m] = LDA(sl, wr * 128 + 64 + m * 16 + l15);
    if (doStage) STAGE_B(sp, i + 2);
    __builtin_amdgcn_s_barrier();
    __builtin_amdgcn_s_setprio(1);
#pragma unroll
    for (int m = 0; m < 4; ++m)
#pragma unroll
      for (int n = 0; n < 4; ++n)
        acc[m + 4][n] = __builtin_amdgcn_mfma_f32_16x16x32_bf16(a[m], b[n], acc[m + 4][n], 0, 0, 0);
    __builtin_amdgcn_s_setprio(0);
    // gate for next iteration's K-tile: retire all but the newest 4 ops
    // (the K-tile staged THIS iteration stays in flight across the barrier)
    if (vm4) asm volatile("s_waitcnt vmcnt(4)" ::: "memory");
    else     asm volatile("s_waitcnt vmcnt(0)" ::: "memory");
    __builtin_amdgcn_s_barrier();
  };

  // prologue: KT0 + KT1 in flight (8 ops); retire KT0, keep KT1 flying
  STAGE_A(0, 0); STAGE_B(0, 0);
  STAGE_A(1, 1); STAGE_B(1, 1);
  asm volatile("s_waitcnt vmcnt(4)" ::: "memory");
  __builtin_amdgcn_s_barrier();

  for (int i = 0; i < KT_N - 2; ++i) ITERATION(i, true, true);
  ITERATION(KT_N - 2, false, false);   // drain: KT31 must land
  ITERATION(KT_N - 1, false, false);

  // epilogue: exp-sum over this tile's 256 cols + target capture
#pragma unroll
  for (int M = 0; M < 8; ++M) {
    const int browbase = bt * BM + wr * 128 + ((M >> 2) << 6) + ((M & 3) << 4) + (lhi << 2);
    float esum[4];
#pragma unroll
    for (int j = 0; j < 4; ++j) {
      const int brow = browbase + j;
      const int t = tg[brow];
      float e = 0.f;
#pragma unroll
      for (int n = 0; n < 4; ++n) {
        float logit = acc[M][n][j] * TINV;
        e += __expf(logit);
        int col = nt * BN + wc * 64 + n * 16 + l15;
        if (col == t) tl[brow] = logit;
      }
      esum[j] = e;
    }
#pragma unroll
    for (int j = 0; j < 4; ++j) {
      float e = esum[j];
      e += __shfl_xor(e, 1, 64);
      e += __shfl_xor(e, 2, 64);
      e += __shfl_xor(e, 4, 64);
      e += __shfl_xor(e, 8, 64);
      if (l15 == 0) atomicAdd(rs + browbase + j, e);
    }
  }
}

// ---------------------------------------------------------------------------
// Kernel 4: loss = mean(log(rowsum) - tgtlog) per modality
// ---------------------------------------------------------------------------
__global__ void loss_kernel(const float* __restrict__ rowsum,
                            const float* __restrict__ tgtlog,
                            float* __restrict__ out) {
  int t = threadIdx.x;  // 512
  float lr = logf(rowsum[t]) - tgtlog[t];
  float li = logf(rowsum[BATCH + t]) - tgtlog[BATCH + t];
#pragma unroll
  for (int m = 1; m < 64; m <<= 1) { lr += __shfl_xor(lr, m, 64); li += __shfl_xor(li, m, 64); }
  __shared__ float sr[8], si[8];
  if ((t & 63) == 0) { sr[t >> 6] = lr; si[t >> 6] = li; }
  __syncthreads();
  if (t == 0) {
    float a = 0.f, b = 0.f;
#pragma unroll
    for (int i = 0; i < 8; ++i) { a += sr[i]; b += si[i]; }
    out[0] = a * (1.0f / BATCH);
    out[1] = b * (1.0f / BATCH);
  }
}

// ---------------------------------------------------------------------------
// Kernel 5: sequential momentum update chains on the copied banks.
// ---------------------------------------------------------------------------
__global__ void mom_kernel(const int* __restrict__ t_rgb,
                           const int* __restrict__ t_ir,
                           const float* __restrict__ xf,   // [2][512][1024]
                           float* __restrict__ out) {      // out + 2 base
  const int i   = blockIdx.x;
  const int mod = blockIdx.y;
  const int* tg = mod ? t_ir : t_rgb;
  const int y = tg[i];
  for (int j = 0; j < i; ++j)
    if (tg[j] == y) return;          // uniform: another block owns this chain

  const float* x = xf + (size_t)mod * BATCH * DIM;
  float* rowp = out + (size_t)mod * NCLUS * DIM + (size_t)y * DIM;

  const int t = threadIdx.x;  // 256
  float2 r0 = ((const float2*)rowp)[t];
  float2 r1 = ((const float2*)rowp)[t + 256];
  __shared__ float red[4];

  for (int j = i; j < BATCH; ++j) {
    if (tg[j] != y) continue;        // uniform
    const float2* xr = (const float2*)(x + (size_t)j * DIM);
    float2 x0 = xr[t], x1 = xr[t + 256];
    r0.x = 0.9f * r0.x + 0.1f * x0.x;
    r0.y = 0.9f * r0.y + 0.1f * x0.y;
    r1.x = 0.9f * r1.x + 0.1f * x1.x;
    r1.y = 0.9f * r1.y + 0.1f * x1.y;
    float ss = r0.x*r0.x + r0.y*r0.y + r1.x*r1.x + r1.y*r1.y;
#pragma unroll
    for (int m = 1; m < 64; m <<= 1) ss += __shfl_xor(ss, m, 64);
    if ((t & 63) == 0) red[t >> 6] = ss;
    __syncthreads();
    float tot = red[0] + red[1] + red[2] + red[3];
    __syncthreads();
    float inv = 1.0f / sqrtf(tot);
    r0.x *= inv; r0.y *= inv; r1.x *= inv; r1.y *= inv;
  }
  ((float2*)rowp)[t] = r0;
  ((float2*)rowp)[t + 256] = r1;
}

// ---------------------------------------------------------------------------
extern "C" void kernel_launch(void* const* d_in, const int* in_sizes, int n_in,
                              void* d_out, int out_size, void* d_ws, size_t ws_size,
                              hipStream_t stream) {
  (void)in_sizes; (void)n_in; (void)out_size; (void)ws_size;
  const float* in_rgb = (const float*)d_in[0];
  const float* in_ir  = (const float*)d_in[1];
  const int*   t_rgb  = (const int*)d_in[2];
  const int*   t_ir   = (const int*)d_in[3];
  const float* f_rgb  = (const float*)d_in[4];
  const float* f_ir   = (const float*)d_in[5];
  float* out = (float*)d_out;

  char* ws = (char*)d_ws;
  float*          xf     = (float*)ws;                       // 4 MB  [2][512][1024] f32
  unsigned short* xb     = (unsigned short*)(ws + (4u<<20)); // 2 MB  [2][512][1024] bf16
  float*          rowsum = (float*)(ws + (6u<<20));          // 2048 f32 (rowsum+tgtlog)
  float*          tgtlog = rowsum + 1024;
  unsigned short* fb     = (unsigned short*)(ws + (8u<<20)); // 64 MB [2][16384][1024] bf16

  nrm_kernel<<<1024, 256, 0, stream>>>(in_rgb, in_ir, xf, xb, rowsum);
  cvtcopy_kernel<<<2048, 256, 0, stream>>>(f_rgb, f_ir, out + 2, fb);
  gemm_lse_kernel<<<dim3(64, 4), 512, 0, stream>>>(xb, fb, t_rgb, t_ir, rowsum, tgtlog);
  mom_kernel<<<dim3(512, 2), 256, 0, stream>>>(t_rgb, t_ir, xf, out + 2);
  loss_kernel<<<1, 512, 0, stream>>>(rowsum, tgtlog, out);
}

// Round 9
// 184.747 us; speedup vs baseline: 1.1838x; 1.0497x over previous
//
#include <hip/hip_runtime.h>
#include <math.h>

#define BATCH 512
#define DIM   1024
#define NCLUS 16384
#define TINV  20.0f   // 1/TEMP

typedef __attribute__((ext_vector_type(4))) float f32x4;
typedef __attribute__((ext_vector_type(2))) float f32x2;
typedef __attribute__((ext_vector_type(8))) short bf16x8;

static __device__ __forceinline__ unsigned short f2bf(float f) {
  unsigned int u = __float_as_uint(f);
  u += 0x7FFFu + ((u >> 16) & 1u);   // round-to-nearest-even
  return (unsigned short)(u >> 16);
}

typedef const __attribute__((address_space(1))) unsigned int* gas1_t;
typedef __attribute__((address_space(3))) unsigned int* las3_t;
// async global->LDS, 16B per lane; LDS dest = wave-uniform base + lane*16
static __device__ __forceinline__ void gload16(const void* g, void* l) {
  __builtin_amdgcn_global_load_lds((gas1_t)g, (las3_t)l, 16, 0, 0);
}

// ---------------------------------------------------------------------------
// Kernel 1: row L2-normalize (both modalities), emit f32 + bf16 copies of x.
// Also zeroes the 2048-float accumulator region (rowsum + tgtlog).
// ---------------------------------------------------------------------------
__global__ void nrm_kernel(const float* __restrict__ in_rgb,
                           const float* __restrict__ in_ir,
                           float* __restrict__ xf,            // [2][512][1024]
                           unsigned short* __restrict__ xb,   // [2][512][1024]
                           float* __restrict__ accum) {       // 2048 floats
  int gid = blockIdx.x * blockDim.x + threadIdx.x;
  if (gid < 2048) accum[gid] = 0.0f;

  int row = blockIdx.x;
  int mod = row >> 9;
  int r   = row & 511;
  const float* in = (mod ? in_ir : in_rgb) + (size_t)r * DIM;
  float* xo          = xf + ((size_t)mod * BATCH + r) * DIM;
  unsigned short* xbo = xb + ((size_t)mod * BATCH + r) * DIM;

  int t = threadIdx.x;
  float4 v = ((const float4*)in)[t];
  float ss = v.x*v.x + v.y*v.y + v.z*v.z + v.w*v.w;
#pragma unroll
  for (int m = 1; m < 64; m <<= 1) ss += __shfl_xor(ss, m, 64);
  __shared__ float red[4];
  if ((t & 63) == 0) red[t >> 6] = ss;
  __syncthreads();
  float inv = 1.0f / fmaxf(sqrtf(red[0] + red[1] + red[2] + red[3]), 1e-12f);
  float4 o = make_float4(v.x * inv, v.y * inv, v.z * inv, v.w * inv);
  ((float4*)xo)[t] = o;
  ushort4 ob = make_ushort4(f2bf(o.x), f2bf(o.y), f2bf(o.z), f2bf(o.w));
  ((ushort4*)xbo)[t] = ob;
}

// ---------------------------------------------------------------------------
// Kernel 2: bank copy to d_out (f32 exact, nontemporal) + bf16 convert of F.
// out is only 8B-aligned (d_out+2 floats) -> f32x2 stores there.
// 8192 blocks: TLP to reach copy BW (round-2 copy hit 5.6 TB/s at this grid).
// ---------------------------------------------------------------------------
__global__ void cvtcopy_kernel(const float* __restrict__ f_rgb,
                               const float* __restrict__ f_ir,
                               float* __restrict__ out,           // out + 2
                               unsigned short* __restrict__ fb) { // [2][16384][1024] bf16
  const size_t n4 = (size_t)NCLUS * DIM / 4;   // f32x4 per bank
  size_t stride = (size_t)gridDim.x * blockDim.x;
  for (size_t i = (size_t)blockIdx.x * blockDim.x + threadIdx.x; i < 2 * n4; i += stride) {
    const f32x4* src = (i < n4) ? ((const f32x4*)f_rgb) + i
                                : ((const f32x4*)f_ir) + (i - n4);
    const f32x4 v = __builtin_nontemporal_load(src);
    f32x2* o2 = (f32x2*)(out + 4 * i);
    __builtin_nontemporal_store((f32x2){v.x, v.y}, o2);
    __builtin_nontemporal_store((f32x2){v.z, v.w}, o2 + 1);
    ((ushort4*)fb)[i] = make_ushort4(f2bf(v.x), f2bf(v.y), f2bf(v.z), f2bf(v.w));
  }
}

// ---------------------------------------------------------------------------
// Kernel 3: 256x256 bf16 MFMA GEMM + fused exp-sum / target capture.
// 512 threads = 8 waves (2 M x 4 N), per-wave output 128x64, acc[8][4].
// K-tile BK=32, 4-slot LDS ring (128 KB), stage KT i+2 at iter i.
// ONE gate per iteration: counted s_waitcnt vmcnt(4) + s_barrier (T4) —
// no mid-iteration barriers (hazard analysis: slot being re-staged was
// last read 2 gates ago; vmcnt(4)+barrier makes all waves' KT i+1 DMA
// visible). 12 ds_read_b128 + 4 gload16 + 32 MFMA per unbarriered body;
// compiler manages lgkmcnt; setprio(1) around the MFMA cluster (T5).
// Conflict-free LDS reads via read-side XOR byte ^= (l15&6)<<3 +
// inverse-swizzled global source chunks (T2, rule #21; conflicts=0 measured).
// grid (64 nt, 4 = mod*2+bt): same-nt blocks are 64 apart -> same XCD.
// ---------------------------------------------------------------------------
#define BM 256
#define BN 256
#define BK 32
#define KT_N (DIM / BK)   // 32 K-tiles

__launch_bounds__(512, 2)
__global__ void gemm_lse_kernel(const unsigned short* __restrict__ xb,
                                const unsigned short* __restrict__ fb,
                                const int* __restrict__ t_rgb,
                                const int* __restrict__ t_ir,
                                float* __restrict__ rowsum,   // [2][512]
                                float* __restrict__ tgtlog) { // [2][512]
  const int nt  = blockIdx.x;        // 0..63
  const int bt  = blockIdx.y & 1;    // batch tile
  const int mod = blockIdx.y >> 1;   // modality

  const unsigned short* X = xb + ((size_t)mod * BATCH + bt * BM) * DIM;
  const unsigned short* F = fb + ((size_t)mod * NCLUS + (size_t)nt * BN) * DIM;
  const int* tg = mod ? t_ir : t_rgb;
  float* rs = rowsum + mod * BATCH;
  float* tl = tgtlog + mod * BATCH;

  __shared__ __align__(16) unsigned short Ab[4][BM * BK];  // 64 KB
  __shared__ __align__(16) unsigned short Bb[4][BN * BK];  // 64 KB

  const int tid  = threadIdx.x;        // 0..511
  const int wid  = tid >> 6;           // 0..7
  const int lane = tid & 63;
  const int wr = wid >> 2, wc = wid & 3;
  const int l15 = lane & 15, lhi = lane >> 4;
  const int sw = (l15 & 6) << 3;       // read-side bank-spread XOR (bytes)

  f32x4 acc[8][4];
#pragma unroll
  for (int m = 0; m < 8; ++m)
#pragma unroll
    for (int n = 0; n < 4; ++n) acc[m][n] = (f32x4){0.f, 0.f, 0.f, 0.f};

  // stage one 16 KB tile (A or B) of K-tile kt into slot sl: 2 gload16/thread.
  // source chunk is inverse-swizzled: cs = (q&3) ^ ((q>>3)&3)  (involution,
  // row q>>2 unchanged) so the XOR'd read below retrieves the right bytes.
  auto STAGE_A = [&](int sl, int kt) {
#pragma unroll
    for (int c = 0; c < 2; ++c) {
      int q = c * 512 + tid;                       // chunk 0..1023
      int cs = (q & 3) ^ ((q >> 3) & 3);
      gload16(X + (size_t)(q >> 2) * DIM + kt * BK + cs * 8,
              &Ab[sl][(c * 512 + wid * 64) * 8]);
    }
  };
  auto STAGE_B = [&](int sl, int kt) {
#pragma unroll
    for (int c = 0; c < 2; ++c) {
      int q = c * 512 + tid;
      int cs = (q & 3) ^ ((q >> 3) & 3);
      gload16(F + (size_t)(q >> 2) * DIM + kt * BK + cs * 8,
              &Bb[sl][(c * 512 + wid * 64) * 8]);
    }
  };
  auto LDA = [&](int sl, int row) {
    return *(const bf16x8*)((const char*)Ab[sl] + ((row * (BK * 2) + lhi * 16) ^ sw));
  };
  auto LDB = [&](int sl, int row) {
    return *(const bf16x8*)((const char*)Bb[sl] + ((row * (BK * 2) + lhi * 16) ^ sw));
  };

  // gate: 4 = keep newest K-tile in flight; 0 = tail drain; -1 = none
  auto ITERATION = [&](int i, bool doStage, int gate) {
    const int sl = i & 3, sp = (i + 2) & 3;
    bf16x8 a[8], b[4];
#pragma unroll
    for (int n = 0; n < 4; ++n) b[n] = LDB(sl, wc * 64 + n * 16 + l15);
#pragma unroll
    for (int m = 0; m < 8; ++m) a[m] = LDA(sl, wr * 128 + m * 16 + l15);
    if (doStage) { STAGE_A(sp, i + 2); STAGE_B(sp, i + 2); }
    __builtin_amdgcn_s_setprio(1);
#pragma unroll
    for (int m = 0; m < 8; ++m)
#pragma unroll
      for (int n = 0; n < 4; ++n)
        acc[m][n] = __builtin_amdgcn_mfma_f32_16x16x32_bf16(a[m], b[n], acc[m][n], 0, 0, 0);
    __builtin_amdgcn_s_setprio(0);
    if (gate >= 0) {
      if (gate == 4) asm volatile("s_waitcnt vmcnt(4)" ::: "memory");
      else           asm volatile("s_waitcnt vmcnt(0)" ::: "memory");
      __builtin_amdgcn_s_barrier();
    }
  };

  // prologue: KT0 + KT1 in flight (8 ops); retire KT0, keep KT1 flying
  STAGE_A(0, 0); STAGE_B(0, 0);
  STAGE_A(1, 1); STAGE_B(1, 1);
  asm volatile("s_waitcnt vmcnt(4)" ::: "memory");
  __builtin_amdgcn_s_barrier();

  for (int i = 0; i < KT_N - 2; ++i) ITERATION(i, true, 4);
  ITERATION(KT_N - 2, false, 0);   // drain: KT31 must land
  ITERATION(KT_N - 1, false, -1);

  // epilogue: exp-sum over this tile's 256 cols + target capture
#pragma unroll
  for (int M = 0; M < 8; ++M) {
    const int browbase = bt * BM + wr * 128 + ((M >> 2) << 6) + ((M & 3) << 4) + (lhi << 2);
    float esum[4];
#pragma unroll
    for (int j = 0; j < 4; ++j) {
      const int brow = browbase + j;
      const int t = tg[brow];
      float e = 0.f;
#pragma unroll
      for (int n = 0; n < 4; ++n) {
        float logit = acc[M][n][j] * TINV;
        e += __expf(logit);
        int col = nt * BN + wc * 64 + n * 16 + l15;
        if (col == t) tl[brow] = logit;
      }
      esum[j] = e;
    }
#pragma unroll
    for (int j = 0; j < 4; ++j) {
      float e = esum[j];
      e += __shfl_xor(e, 1, 64);
      e += __shfl_xor(e, 2, 64);
      e += __shfl_xor(e, 4, 64);
      e += __shfl_xor(e, 8, 64);
      if (l15 == 0) atomicAdd(rs + browbase + j, e);
    }
  }
}

// ---------------------------------------------------------------------------
// Kernel 4: loss = mean(log(rowsum) - tgtlog) per modality
// ---------------------------------------------------------------------------
__global__ void loss_kernel(const float* __restrict__ rowsum,
                            const float* __restrict__ tgtlog,
                            float* __restrict__ out) {
  int t = threadIdx.x;  // 512
  float lr = logf(rowsum[t]) - tgtlog[t];
  float li = logf(rowsum[BATCH + t]) - tgtlog[BATCH + t];
#pragma unroll
  for (int m = 1; m < 64; m <<= 1) { lr += __shfl_xor(lr, m, 64); li += __shfl_xor(li, m, 64); }
  __shared__ float sr[8], si[8];
  if ((t & 63) == 0) { sr[t >> 6] = lr; si[t >> 6] = li; }
  __syncthreads();
  if (t == 0) {
    float a = 0.f, b = 0.f;
#pragma unroll
    for (int i = 0; i < 8; ++i) { a += sr[i]; b += si[i]; }
    out[0] = a * (1.0f / BATCH);
    out[1] = b * (1.0f / BATCH);
  }
}

// ---------------------------------------------------------------------------
// Kernel 5: sequential momentum update chains on the copied banks.
// ---------------------------------------------------------------------------
__global__ void mom_kernel(const int* __restrict__ t_rgb,
                           const int* __restrict__ t_ir,
                           const float* __restrict__ xf,   // [2][512][1024]
                           float* __restrict__ out) {      // out + 2 base
  const int i   = blockIdx.x;
  const int mod = blockIdx.y;
  const int* tg = mod ? t_ir : t_rgb;
  const int y = tg[i];
  for (int j = 0; j < i; ++j)
    if (tg[j] == y) return;          // uniform: another block owns this chain

  const float* x = xf + (size_t)mod * BATCH * DIM;
  float* rowp = out + (size_t)mod * NCLUS * DIM + (size_t)y * DIM;

  const int t = threadIdx.x;  // 256
  float2 r0 = ((const float2*)rowp)[t];
  float2 r1 = ((const float2*)rowp)[t + 256];
  __shared__ float red[4];

  for (int j = i; j < BATCH; ++j) {
    if (tg[j] != y) continue;        // uniform
    const float2* xr = (const float2*)(x + (size_t)j * DIM);
    float2 x0 = xr[t], x1 = xr[t + 256];
    r0.x = 0.9f * r0.x + 0.1f * x0.x;
    r0.y = 0.9f * r0.y + 0.1f * x0.y;
    r1.x = 0.9f * r1.x + 0.1f * x1.x;
    r1.y = 0.9f * r1.y + 0.1f * x1.y;
    float ss = r0.x*r0.x + r0.y*r0.y + r1.x*r1.x + r1.y*r1.y;
#pragma unroll
    for (int m = 1; m < 64; m <<= 1) ss += __shfl_xor(ss, m, 64);
    if ((t & 63) == 0) red[t >> 6] = ss;
    __syncthreads();
    float tot = red[0] + red[1] + red[2] + red[3];
    __syncthreads();
    float inv = 1.0f / sqrtf(tot);
    r0.x *= inv; r0.y *= inv; r1.x *= inv; r1.y *= inv;
  }
  ((float2*)rowp)[t] = r0;
  ((float2*)rowp)[t + 256] = r1;
}

// ---------------------------------------------------------------------------
extern "C" void kernel_launch(void* const* d_in, const int* in_sizes, int n_in,
                              void* d_out, int out_size, void* d_ws, size_t ws_size,
                              hipStream_t stream) {
  (void)in_sizes; (void)n_in; (void)out_size; (void)ws_size;
  const float* in_rgb = (const float*)d_in[0];
  const float* in_ir  = (const float*)d_in[1];
  const int*   t_rgb  = (const int*)d_in[2];
  const int*   t_ir   = (const int*)d_in[3];
  const float* f_rgb  = (const float*)d_in[4];
  const float* f_ir   = (const float*)d_in[5];
  float* out = (float*)d_out;

  char* ws = (char*)d_ws;
  float*          xf     = (float*)ws;                       // 4 MB  [2][512][1024] f32
  unsigned short* xb     = (unsigned short*)(ws + (4u<<20)); // 2 MB  [2][512][1024] bf16
  float*          rowsum = (float*)(ws + (6u<<20));          // 2048 f32 (rowsum+tgtlog)
  float*          tgtlog = rowsum + 1024;
  unsigned short* fb     = (unsigned short*)(ws + (8u<<20)); // 64 MB [2][16384][1024] bf16

  nrm_kernel<<<1024, 256, 0, stream>>>(in_rgb, in_ir, xf, xb, rowsum);
  cvtcopy_kernel<<<8192, 256, 0, stream>>>(f_rgb, f_ir, out + 2, fb);
  gemm_lse_kernel<<<dim3(64, 4), 512, 0, stream>>>(xb, fb, t_rgb, t_ir, rowsum, tgtlog);
  mom_kernel<<<dim3(512, 2), 256, 0, stream>>>(t_rgb, t_ir, xf, out + 2);
  loss_kernel<<<1, 512, 0, stream>>>(rowsum, tgtlog, out);
}